// Round 9
// baseline (281.635 us; speedup 1.0000x reference)
//
#include <hip/hip_runtime.h>
#include <stdint.h>

#define BB 1024
#define NN 400
#define EE 128
#define DD 128
#define NSLOT 64
#define GTS2 232             // GT row stride in shorts (464B rows -> even bank spread)

typedef float f32x4 __attribute__((ext_vector_type(4)));
typedef short bf16x8 __attribute__((ext_vector_type(8)));

__device__ __forceinline__ short f2bf(float f) {
    uint32_t u = __builtin_bit_cast(uint32_t, f);
    u += 0x7fffu + ((u >> 16) & 1u);
    return (short)(u >> 16);
}

__device__ __forceinline__ float bf2f(short s) {
    return __builtin_bit_cast(float, (uint32_t)((uint16_t)s) << 16);
}

__device__ __forceinline__ bf16x8 cvt8(const f32x4 a, const f32x4 b) {
    bf16x8 r;
    r[0] = f2bf(a[0]); r[1] = f2bf(a[1]); r[2] = f2bf(a[2]); r[3] = f2bf(a[3]);
    r[4] = f2bf(b[0]); r[5] = f2bf(b[1]); r[6] = f2bf(b[2]); r[7] = f2bf(b[3]);
    return r;
}

__device__ __forceinline__ void gload16(const void* g, void* l) {
    __builtin_amdgcn_global_load_lds(
        (const __attribute__((address_space(1))) void*)g,
        (__attribute__((address_space(3))) void*)l, 16, 0, 0);
}

// K0: one-shot convert W1 (32768) and W2 (16384) to bf16 in workspace.
__global__ __launch_bounds__(256)
void k0_cvtw(const float* __restrict__ W1, const float* __restrict__ W2,
             unsigned short* __restrict__ W1b, unsigned short* __restrict__ W2b)
{
    int i = blockIdx.x * 256 + threadIdx.x;
    if (i < 32768) W1b[i] = (unsigned short)f2bf(W1[i]);
    if (i < 16384) W2b[i] = (unsigned short)f2bf(W2[i]);
}

// K1: one 1024-thread block per b. LDS 154KB.
//   A-path: f32 3-buffer LDS ring via global_load_lds (2 instr/wave/tile,
//   per-wave-owned 2KB slices -> barrier-free, counted vmcnt(2)).
//   Source-chunk XOR swizzle (LDS[r][x] = A[r][x^(r&7)]) -> bank-even reads.
//   GT [128][232] bf16 resident, staged in 2 k-halves (barriers only at s==7).
//   Tile 12 tail (k 400..415): A addr clamped to row start; GT zeros nullify.
//   Stage 2 fused: P'->Ps swizzled (aliases A ring), h = X @ W1b^T + b1,
//   h bf16 + BN1 slot stats.
__global__ __launch_bounds__(1024, 1)
void k1_gemm(const float* __restrict__ gout, const float* __restrict__ ss,
             const float* __restrict__ es, const unsigned short* __restrict__ W1b,
             const float* __restrict__ b1, unsigned short* __restrict__ h,
             float* __restrict__ stats1)
{
    __shared__ short lds[78848];           // 154 KB
    short* GT = lds;                       // [128][232] bf16 (59392 B)
    float* Ab = (float*)&lds[29696];       // 3 x [256][32] f32 (98304 B)
    short* Ps = &lds[29696];               // [256][128] bf16 (64 KB), phase 2

    const int b   = blockIdx.x;
    const int t   = threadIdx.x;
    const int w   = t >> 6;                // wave 0..15
    const int l   = t & 63;
    const int l15 = l & 15;
    const int l4  = l >> 4;                // 0..3
    const int jrow = l >> 3;               // 0..7 (staging row-in-instr)
    const int xchk = l & 7;                // staging chunk-in-row

    // issue 2 global_load_lds staging wave w's 16 A rows of one 32-k tile
    auto issueA = [&](int tile) {
        float* dst = Ab + (tile % 3) * 8192 + w * 512;   // wave-uniform
        const int k0 = tile * 32;
#pragma unroll
        for (int j = 0; j < 2; ++j) {
            int r = w * 16 + j * 8 + jrow;               // 0..255
            const float* base = ((r < 128) ? ss : es) + ((size_t)b * EE + (r & 127)) * NN;
            int kc = k0 + ((xchk ^ (r & 7)) << 2);
            if (kc >= NN) kc = 0;                        // tile-12 tail; GT zeros nullify
            gload16(base + kc, dst + j * 256);
        }
    };

    // GT staging (k-quads packed, b64 writes)
    const float* gb = gout + (size_t)b * NN * DD + (t & 127);
    auto stageGT = [&](int koff, int nq) {
        const int qb = t >> 7;             // 0..7
        short* row = &GT[(t & 127) * GTS2];
        for (int q = qb; q < nq; q += 8) {
            int kg = koff + 4 * q;
            float v0 = (kg     < NN) ? gb[(size_t)(kg)     * DD] : 0.f;
            float v1 = (kg + 1 < NN) ? gb[(size_t)(kg + 1) * DD] : 0.f;
            float v2 = (kg + 2 < NN) ? gb[(size_t)(kg + 2) * DD] : 0.f;
            float v3 = (kg + 3 < NN) ? gb[(size_t)(kg + 3) * DD] : 0.f;
            uint32_t lo = (uint32_t)(uint16_t)f2bf(v0) | ((uint32_t)(uint16_t)f2bf(v1) << 16);
            uint32_t hi = (uint32_t)(uint16_t)f2bf(v2) | ((uint32_t)(uint16_t)f2bf(v3) << 16);
            *(uint64_t*)&row[4 * q] = ((uint64_t)hi << 32) | lo;
        }
    };

    issueA(0);
    issueA(1);
    stageGT(0, 56);                        // k 0..223
    __syncthreads();

    // ---- K-loop: P(16 rows x 128 d per wave), barrier-free except s==7 ----
    f32x4 acc[8];
#pragma unroll
    for (int cf = 0; cf < 8; ++cf) acc[cf] = f32x4{0.f, 0.f, 0.f, 0.f};

#pragma unroll
    for (int s = 0; s < 13; ++s) {
        if (s == 7) {
            __syncthreads();               // all GT half-0 reads done
            stageGT(224, 48);              // k 224..415 (zeros past 399)
            __syncthreads();
        }
        if (s == 12) { asm volatile("s_waitcnt vmcnt(0)" ::: "memory"); }
        else         { asm volatile("s_waitcnt vmcnt(2)" ::: "memory"); }
        if (s + 2 < 13) issueA(s + 2);

        const float* ap = Ab + (s % 3) * 8192 + w * 512 + l15 * 32;
        f32x4 alo = *(const f32x4*)(ap + ((((2 * l4)     ^ (l15 & 7))) << 2));
        f32x4 ahi = *(const f32x4*)(ap + ((((2 * l4 + 1) ^ (l15 & 7))) << 2));
        bf16x8 a = cvt8(alo, ahi);

        const int k0 = (s < 7 ? s * 32 : (s - 7) * 32) + l4 * 8;
#pragma unroll
        for (int cf = 0; cf < 8; ++cf) {
            bf16x8 gf = *(const bf16x8*)&GT[(cf * 16 + l15) * GTS2 + k0];
            acc[cf] = __builtin_amdgcn_mfma_f32_16x16x32_bf16(a, gf, acc[cf], 0, 0, 0);
        }
    }
    __syncthreads();                       // all loops + DMA done; A ring dead

    // ---- phase 2a: write P' swizzled into Ps[256][128] ----
#pragma unroll
    for (int cf = 0; cf < 8; ++cf)
#pragma unroll
        for (int r = 0; r < 4; ++r) {
            int row = w * 16 + l4 * 4 + r;         // 0..255 (S rows, then T rows)
            int col = cf * 16 + l15;
            Ps[row * 128 + (((col >> 3) ^ (row & 7)) << 3) + (col & 7)] = f2bf(acc[cf][r]);
        }
    __syncthreads();

    // ---- phase 2b: h(16 e-rows x 64 j per wave) = X @ W1^T (W1b from L2) ----
    const int mt = w >> 1;                 // 0..7
    const int jh = w & 1;
    f32x4 acc2[4];
#pragma unroll
    for (int cf = 0; cf < 4; ++cf) acc2[cf] = f32x4{0.f, 0.f, 0.f, 0.f};

#pragma unroll
    for (int kf = 0; kf < 8; ++kf) {
        int roff = (kf >= 4) ? 128 : 0;
        int row  = roff + mt * 16 + l15;
        int cb   = (kf & 3) * 4 + l4;
        bf16x8 xf = *(const bf16x8*)&Ps[row * 128 + ((cb ^ (row & 7)) << 3)];
#pragma unroll
        for (int cf = 0; cf < 4; ++cf) {
            int j = jh * 64 + cf * 16 + l15;
            bf16x8 wf = *(const bf16x8*)&W1b[(size_t)j * 256 + kf * 32 + l4 * 8];
            acc2[cf] = __builtin_amdgcn_mfma_f32_16x16x32_bf16(xf, wf, acc2[cf], 0, 0, 0);
        }
    }
    __syncthreads();                       // Ps dead; red live

    // ---- phase 2c: bias, store h (bf16), BN1 stats ----
    float* red = (float*)lds;
    float s_r[4] = {0.f, 0.f, 0.f, 0.f};
    float q_r[4] = {0.f, 0.f, 0.f, 0.f};
#pragma unroll
    for (int cf = 0; cf < 4; ++cf) {
        float bv = b1[jh * 64 + cf * 16 + l15];
        f32x4 v = acc2[cf] + bv;
#pragma unroll
        for (int r = 0; r < 4; ++r) {
            int e = mt * 16 + l4 * 4 + r;
            h[((size_t)b * EE + e) * DD + jh * 64 + cf * 16 + l15] = (unsigned short)f2bf(v[r]);
            s_r[r] += v[r];
            q_r[r] += v[r] * v[r];
        }
    }
#pragma unroll
    for (int r = 0; r < 4; ++r) {
        float s = s_r[r], q = q_r[r];
        s += __shfl_xor(s, 1); s += __shfl_xor(s, 2); s += __shfl_xor(s, 4); s += __shfl_xor(s, 8);
        q += __shfl_xor(q, 1); q += __shfl_xor(q, 2); q += __shfl_xor(q, 4); q += __shfl_xor(q, 8);
        if (l15 == 0) {
            int e = mt * 16 + l4 * 4 + r;
            red[(e << 1) | jh]         = s;
            red[256 + ((e << 1) | jh)] = q;
        }
    }
    __syncthreads();
    if (t < 128) {
        float s = red[2 * t] + red[2 * t + 1];
        float q = red[256 + 2 * t] + red[256 + 2 * t + 1];
        int slot = b & (NSLOT - 1);
        atomicAdd(&stats1[slot * 256 + t], s);
        atomicAdd(&stats1[slot * 256 + 128 + t], q);
    }
}

// K3: per b: finalize BN1, normalize+relu h(bf16) -> bf16 LDS,
// h2 = X @ W2b^T + b2 -> IN-PLACE over h (bf16), BN2 stats.
__global__ __launch_bounds__(256, 4)
void k3_gemm(unsigned short* h, const unsigned short* __restrict__ W2b,
             const float* __restrict__ b2, const float* __restrict__ g1,
             const float* __restrict__ bt1,
             const float* __restrict__ stats1, float* __restrict__ stats2)
{
    __shared__ short Xs[128 * 128];
    __shared__ float sc[128];
    __shared__ float sh[128];
    const int b   = blockIdx.x;
    const int t   = threadIdx.x;
    const int w   = t >> 6;
    const int l15 = t & 15;
    const int l4  = (t >> 4) & 3;

    if (t < 128) {
        float sm = 0.f, sq = 0.f;
#pragma unroll 8
        for (int sl = 0; sl < NSLOT; ++sl) {
            sm += stats1[sl * 256 + t];
            sq += stats1[sl * 256 + 128 + t];
        }
        const float inv_n = 1.0f / (1024.0f * 128.0f);
        float m    = sm * inv_n;
        float var  = sq * inv_n - m * m;
        float rstd = rsqrtf(var + 1e-5f);
        float s    = rstd * g1[t];
        sc[t] = s;
        sh[t] = bt1[t] - m * s;
    }
    __syncthreads();

    {
        const int c8 = t & 15;
        const int eb = t >> 4;
#pragma unroll
        for (int p = 0; p < 8; ++p) {
            int e = eb + 16 * p;
            bf16x8 v8 = *(const bf16x8*)&h[((size_t)b * EE + e) * DD + c8 * 8];
            float s = sc[e], s0 = sh[e];
            bf16x8 o;
#pragma unroll
            for (int i = 0; i < 8; ++i)
                o[i] = f2bf(fmaxf(fmaf(bf2f(v8[i]), s, s0), 0.0f));
            *(bf16x8*)&Xs[e * 128 + ((c8 ^ (e & 7)) << 3)] = o;
        }
    }
    __syncthreads();

    f32x4 acc[8][2];
#pragma unroll
    for (int i = 0; i < 8; ++i) {
        acc[i][0] = f32x4{0.f, 0.f, 0.f, 0.f};
        acc[i][1] = f32x4{0.f, 0.f, 0.f, 0.f};
    }
#pragma unroll
    for (int kf = 0; kf < 4; ++kf) {
        const int k0 = kf * 32;
        const int cb = (k0 >> 3) + l4;
        bf16x8 af[8];
#pragma unroll
        for (int rf = 0; rf < 8; ++rf) {
            int row = rf * 16 + l15;
            af[rf] = *(const bf16x8*)&Xs[row * 128 + ((cb ^ (row & 7)) * 8)];
        }
#pragma unroll
        for (int cf = 0; cf < 2; ++cf) {
            int j = w * 32 + cf * 16 + l15;
            bf16x8 bfr = *(const bf16x8*)&W2b[(size_t)j * 128 + k0 + l4 * 8];
#pragma unroll
            for (int rf = 0; rf < 8; ++rf)
                acc[rf][cf] = __builtin_amdgcn_mfma_f32_16x16x32_bf16(af[rf], bfr, acc[rf][cf], 0, 0, 0);
        }
    }

    __syncthreads();
    float* red = (float*)Xs;
    const float bj0 = b2[w * 32 + l15];
    const float bj1 = b2[w * 32 + 16 + l15];
    const int j0 = w * 32 + l15;
#pragma unroll
    for (int rf = 0; rf < 8; ++rf) {
        f32x4 v0 = acc[rf][0] + bj0;
        f32x4 v1 = acc[rf][1] + bj1;
        int elb = rf * 16 + l4 * 4;
#pragma unroll
        for (int r = 0; r < 4; ++r) {
            unsigned short* op = h + (size_t)(b * EE + elb + r) * DD;
            op[j0]      = (unsigned short)f2bf(v0[r]);
            op[j0 + 16] = (unsigned short)f2bf(v1[r]);
            float s = v0[r] + v1[r];
            float q = v0[r] * v0[r] + v1[r] * v1[r];
            s += __shfl_xor(s, 1); s += __shfl_xor(s, 2); s += __shfl_xor(s, 4); s += __shfl_xor(s, 8);
            q += __shfl_xor(q, 1); q += __shfl_xor(q, 2); q += __shfl_xor(q, 4); q += __shfl_xor(q, 8);
            if (l15 == 0) {
                red[(elb + r) * 4 + w]       = s;
                red[512 + (elb + r) * 4 + w] = q;
            }
        }
    }
    __syncthreads();
    if (t < 128) {
        float s = red[t * 4] + red[t * 4 + 1] + red[t * 4 + 2] + red[t * 4 + 3];
        float q = red[512 + t * 4] + red[512 + t * 4 + 1] + red[512 + t * 4 + 2] + red[512 + t * 4 + 3];
        int slot = b & (NSLOT - 1);
        atomicAdd(&stats2[slot * 256 + t], s);
        atomicAdd(&stats2[slot * 256 + 128 + t], q);
    }
}

// K5: finalize BN2, out = relu(eout + h2*scale + shift); h2 is bf16.
__global__ __launch_bounds__(256)
void k5_final(const unsigned short* __restrict__ h2, const float* __restrict__ eout,
              const float* __restrict__ g2, const float* __restrict__ bt2,
              float* __restrict__ out, const float* __restrict__ stats2)
{
    __shared__ float sc[128];
    __shared__ float sh[128];
    const int t = threadIdx.x;
    if (t < 128) {
        float sm = 0.f, sq = 0.f;
#pragma unroll 8
        for (int sl = 0; sl < NSLOT; ++sl) {
            sm += stats2[sl * 256 + t];
            sq += stats2[sl * 256 + 128 + t];
        }
        const float inv_n = 1.0f / (1024.0f * 128.0f);
        float m    = sm * inv_n;
        float var  = sq * inv_n - m * m;
        float rstd = rsqrtf(var + 1e-5f);
        float s    = rstd * g2[t];
        sc[t] = s;
        sh[t] = bt2[t] - m * s;
    }
    __syncthreads();

    const int total8 = BB * EE * DD / 8;
    for (int i8 = blockIdx.x * blockDim.x + t; i8 < total8; i8 += gridDim.x * blockDim.x) {
        int e = (i8 >> 4) & 127;
        bf16x8 v8 = *(const bf16x8*)(h2 + (size_t)i8 * 8);
        f32x4 u0 = *(const f32x4*)(eout + (size_t)i8 * 8);
        f32x4 u1 = *(const f32x4*)(eout + (size_t)i8 * 8 + 4);
        float s = sc[e], s0 = sh[e];
        f32x4 o0, o1;
#pragma unroll
        for (int i = 0; i < 4; ++i) {
            o0[i] = fmaxf(u0[i] + fmaf(bf2f(v8[i]), s, s0), 0.0f);
            o1[i] = fmaxf(u1[i] + fmaf(bf2f(v8[i + 4]), s, s0), 0.0f);
        }
        *(f32x4*)(out + (size_t)i8 * 8)     = o0;
        *(f32x4*)(out + (size_t)i8 * 8 + 4) = o1;
    }
}

extern "C" void kernel_launch(void* const* d_in, const int* in_sizes, int n_in,
                              void* d_out, int out_size, void* d_ws, size_t ws_size,
                              hipStream_t stream)
{
    const float* gout  = (const float*)d_in[0];
    const float* eout  = (const float*)d_in[1];
    const float* ss    = (const float*)d_in[2];
    const float* es    = (const float*)d_in[3];
    const float* W1    = (const float*)d_in[4];
    const float* b1    = (const float*)d_in[5];
    const float* W2    = (const float*)d_in[6];
    const float* b2    = (const float*)d_in[7];
    const float* g1    = (const float*)d_in[8];
    const float* bt1   = (const float*)d_in[9];
    const float* g2    = (const float*)d_in[10];
    const float* bt2   = (const float*)d_in[11];

    float* stats1 = (float*)d_ws;                              // [64][256]
    float* stats2 = stats1 + NSLOT * 256;                      // [64][256]
    unsigned short* W1b = (unsigned short*)(stats2 + NSLOT * 256);  // 32768 bf16
    unsigned short* W2b = W1b + 32768;                         // 16384 bf16
    unsigned short* h   = W2b + 16384;                         // [B][E][D] bf16 (h, then h2 in-place)
    float* out    = (float*)d_out;

    hipMemsetAsync((void*)stats1, 0, 2 * NSLOT * 256 * sizeof(float), stream);
    k0_cvtw<<<dim3(128), dim3(256), 0, stream>>>(W1, W2, W1b, W2b);
    k1_gemm<<<dim3(BB), dim3(1024), 0, stream>>>(gout, ss, es, W1b, b1, h, stats1);
    k3_gemm<<<dim3(BB), dim3(256), 0, stream>>>(h, W2b, b2, g1, bt1, stats1, stats2);
    k5_final<<<dim3(2048), dim3(256), 0, stream>>>(h, eout, g2, bt2, out, stats2);
}

// Round 10
// 275.382 us; speedup vs baseline: 1.0227x; 1.0227x over previous
//
#include <hip/hip_runtime.h>
#include <stdint.h>

#define BB 1024
#define NN 400
#define EE 128
#define DD 128
#define NSLOT 64
#define GTS2 232             // GT row stride in shorts (k-half + pad)

typedef float f32x4 __attribute__((ext_vector_type(4)));
typedef short bf16x8 __attribute__((ext_vector_type(8)));

__device__ __forceinline__ short f2bf(float f) {
    uint32_t u = __builtin_bit_cast(uint32_t, f);
    u += 0x7fffu + ((u >> 16) & 1u);
    return (short)(u >> 16);
}

__device__ __forceinline__ float bf2f(short s) {
    return __builtin_bit_cast(float, (uint32_t)((uint16_t)s) << 16);
}

__device__ __forceinline__ bf16x8 cvt8(const f32x4 a, const f32x4 b) {
    bf16x8 r;
    r[0] = f2bf(a[0]); r[1] = f2bf(a[1]); r[2] = f2bf(a[2]); r[3] = f2bf(a[3]);
    r[4] = f2bf(b[0]); r[5] = f2bf(b[1]); r[6] = f2bf(b[2]); r[7] = f2bf(b[3]);
    return r;
}

// K0: one-shot convert W1 (32768) and W2 (16384) to bf16 in workspace.
__global__ __launch_bounds__(256)
void k0_cvtw(const float* __restrict__ W1, const float* __restrict__ W2,
             unsigned short* __restrict__ W1b, unsigned short* __restrict__ W2b)
{
    int i = blockIdx.x * 256 + threadIdx.x;
    if (i < 32768) W1b[i] = (unsigned short)f2bf(W1[i]);
    if (i < 16384) W2b[i] = (unsigned short)f2bf(W2[i]);
}

// K1: 2048 blocks x 512 threads (8 waves), one E-half (64 edges) per block.
//   LDS 59.4KB -> 2 blocks/CU truly co-resident ((512,4): 16 waves/CU).
//   XCD-chunked block swizzle: pair (2i,2i+1) shares gout[b] on one XCD L2.
//   GT [128][232] bf16, staged in two k-halves (barriers only at s==7).
//   K-loop: A direct global->reg (2-deep raw-f32 ring, cvt deferred 2 iters),
//   8 ds_read_b128 + 8 MFMA per step, setprio around MFMA cluster.
//   Fused stage 2: P'->Ps[128][128] swizzled (aliases GT), h = X @ W1b^T + b1,
//   h bf16 + BN1 slot stats.
__global__ __launch_bounds__(512, 4)
void k1_gemm(const float* __restrict__ gout, const float* __restrict__ ss,
             const float* __restrict__ es, const unsigned short* __restrict__ W1b,
             const float* __restrict__ b1, unsigned short* __restrict__ h,
             float* __restrict__ stats1)
{
    __shared__ short lds[29696];           // 59392 B
    short* GT = lds;                       // [128][232] bf16
    short* Ps = lds;                       // [128][128] bf16, phase 2 (aliases GT)

    const int s_  = blockIdx.x;
    const int wk  = (s_ & 7) * 256 + (s_ >> 3);   // XCD-chunked work id
    const int b   = wk >> 1;
    const int e0  = (wk & 1) * 64;
    const int t   = threadIdx.x;
    const int w   = t >> 6;                // wave 0..7
    const int l   = t & 63;
    const int l15 = l & 15;
    const int l4  = l >> 4;                // 0..3
    const int kkoff = l4 * 8;

    // A rows: waves 0-3 -> S rows e0+(w*16..), waves 4-7 -> T rows
    const float* abase = ((w < 4) ? ss : es) + ((size_t)b * EE + e0 + (w & 3) * 16 + l15) * NN;

    // pre-issue A ring for K-steps 0,1 (raw f32; cvt deferred)
    f32x4 pa0 = *(const f32x4*)(abase + kkoff);
    f32x4 pa1 = *(const f32x4*)(abase + kkoff + 4);
    f32x4 pb0 = *(const f32x4*)(abase + 32 + kkoff);
    f32x4 pb1 = *(const f32x4*)(abase + 32 + kkoff + 4);

    // GT staging: k-quads packed to b64 (global k = koff + 4q -> GT slot 4q)
    const float* gb = gout + (size_t)b * NN * DD + (t & 127);
    auto stageGT = [&](int koff, int nq) {
        const int qb = t >> 7;             // 0..3
        short* row = &GT[(t & 127) * GTS2];
        for (int q = qb; q < nq; q += 4) {
            int kg = koff + 4 * q;
            float v0 = (kg     < NN) ? gb[(size_t)(kg)     * DD] : 0.f;
            float v1 = (kg + 1 < NN) ? gb[(size_t)(kg + 1) * DD] : 0.f;
            float v2 = (kg + 2 < NN) ? gb[(size_t)(kg + 2) * DD] : 0.f;
            float v3 = (kg + 3 < NN) ? gb[(size_t)(kg + 3) * DD] : 0.f;
            uint32_t lo = (uint32_t)(uint16_t)f2bf(v0) | ((uint32_t)(uint16_t)f2bf(v1) << 16);
            uint32_t hi = (uint32_t)(uint16_t)f2bf(v2) | ((uint32_t)(uint16_t)f2bf(v3) << 16);
            *(uint64_t*)&row[4 * q] = ((uint64_t)hi << 32) | lo;
        }
    };

    stageGT(0, 56);                        // k 0..223
    __syncthreads();

    // ---- K-loop: P(16 rows x 128 d per wave), barrier-free except s==7 ----
    f32x4 acc[8];
#pragma unroll
    for (int cf = 0; cf < 8; ++cf) acc[cf] = f32x4{0.f, 0.f, 0.f, 0.f};

#pragma unroll
    for (int s = 0; s < 13; ++s) {
        if (s == 7) {
            __syncthreads();               // all GT half-0 reads done
            stageGT(224, 48);              // k 224..415 (zeros past 399)
            __syncthreads();
        }
        bf16x8 a = cvt8(pa0, pa1);         // loads from 2 iterations ago
        pa0 = pb0; pa1 = pb1;
        const int sn = s + 2;
        if (sn < 12) {
            pb0 = *(const f32x4*)(abase + sn * 32 + kkoff);
            pb1 = *(const f32x4*)(abase + sn * 32 + kkoff + 4);
        } else if (sn == 12) {
            int kk = 384 + kkoff;
            pb0 = f32x4{0.f, 0.f, 0.f, 0.f};
            pb1 = f32x4{0.f, 0.f, 0.f, 0.f};
            if (kk < NN)     pb0 = *(const f32x4*)(abase + kk);
            if (kk + 4 < NN) pb1 = *(const f32x4*)(abase + kk + 4);
        }
        const int k0 = (s < 7 ? s * 32 : (s - 7) * 32) + kkoff;
        __builtin_amdgcn_s_setprio(1);
#pragma unroll
        for (int cf = 0; cf < 8; ++cf) {
            bf16x8 gf = *(const bf16x8*)&GT[(cf * 16 + l15) * GTS2 + k0];
            acc[cf] = __builtin_amdgcn_mfma_f32_16x16x32_bf16(a, gf, acc[cf], 0, 0, 0);
        }
        __builtin_amdgcn_s_setprio(0);
    }
    __syncthreads();                       // GT dead; Ps live

    // ---- phase 2a: write P' swizzled into Ps[128][128] ----
    // rows 0..63 = S-edges (waves 0-3), rows 64..127 = T-edges (waves 4-7)
#pragma unroll
    for (int cf = 0; cf < 8; ++cf)
#pragma unroll
        for (int r = 0; r < 4; ++r) {
            int row = ((w < 4) ? 0 : 64) + (w & 3) * 16 + l4 * 4 + r;
            int col = cf * 16 + l15;
            Ps[row * 128 + (((col >> 3) ^ (row & 7)) << 3) + (col & 7)] = f2bf(acc[cf][r]);
        }
    __syncthreads();

    // ---- phase 2b: h(16 e-rows x 64 j per wave) = X @ W1^T (W1b from L2) ----
    const int mt = w >> 1;                 // 0..3 (16-row e-tile)
    const int jh = w & 1;                  // j-half
    f32x4 acc2[4];
#pragma unroll
    for (int cf = 0; cf < 4; ++cf) acc2[cf] = f32x4{0.f, 0.f, 0.f, 0.f};

#pragma unroll
    for (int kf = 0; kf < 8; ++kf) {
        int roff = (kf >= 4) ? 64 : 0;     // k<128: S rows; k>=128: T rows
        int row  = roff + mt * 16 + l15;
        int cb   = (kf & 3) * 4 + l4;
        bf16x8 xf = *(const bf16x8*)&Ps[row * 128 + ((cb ^ (row & 7)) << 3)];
#pragma unroll
        for (int cf = 0; cf < 4; ++cf) {
            int j = jh * 64 + cf * 16 + l15;
            bf16x8 wf = *(const bf16x8*)&W1b[(size_t)j * 256 + kf * 32 + l4 * 8];
            acc2[cf] = __builtin_amdgcn_mfma_f32_16x16x32_bf16(xf, wf, acc2[cf], 0, 0, 0);
        }
    }
    __syncthreads();                       // Ps dead; red live

    // ---- phase 2c: bias, store h (bf16), BN1 stats (per-edge channels) ----
    float* red = (float*)lds;              // [128] sums + [128] sumsq
    float s_r[4] = {0.f, 0.f, 0.f, 0.f};
    float q_r[4] = {0.f, 0.f, 0.f, 0.f};
#pragma unroll
    for (int cf = 0; cf < 4; ++cf) {
        float bv = b1[jh * 64 + cf * 16 + l15];
        f32x4 v = acc2[cf] + bv;
#pragma unroll
        for (int r = 0; r < 4; ++r) {
            int e = mt * 16 + l4 * 4 + r;  // 0..63 within half
            h[((size_t)b * EE + e0 + e) * DD + jh * 64 + cf * 16 + l15] = (unsigned short)f2bf(v[r]);
            s_r[r] += v[r];
            q_r[r] += v[r] * v[r];
        }
    }
#pragma unroll
    for (int r = 0; r < 4; ++r) {
        float s = s_r[r], q = q_r[r];
        s += __shfl_xor(s, 1); s += __shfl_xor(s, 2); s += __shfl_xor(s, 4); s += __shfl_xor(s, 8);
        q += __shfl_xor(q, 1); q += __shfl_xor(q, 2); q += __shfl_xor(q, 4); q += __shfl_xor(q, 8);
        if (l15 == 0) {
            int e = mt * 16 + l4 * 4 + r;
            red[(e << 1) | jh]         = s;
            red[128 + ((e << 1) | jh)] = q;
        }
    }
    __syncthreads();
    if (t < 64) {
        float s = red[2 * t] + red[2 * t + 1];
        float q = red[128 + 2 * t] + red[128 + 2 * t + 1];
        int slot = wk & (NSLOT - 1);
        atomicAdd(&stats1[slot * 256 + e0 + t], s);
        atomicAdd(&stats1[slot * 256 + 128 + e0 + t], q);
    }
}

// K3: per b: finalize BN1, normalize+relu h(bf16) -> bf16 LDS,
// h2 = X @ W2b^T + b2 -> IN-PLACE over h (bf16), BN2 stats.
__global__ __launch_bounds__(256, 4)
void k3_gemm(unsigned short* h, const unsigned short* __restrict__ W2b,
             const float* __restrict__ b2, const float* __restrict__ g1,
             const float* __restrict__ bt1,
             const float* __restrict__ stats1, float* __restrict__ stats2)
{
    __shared__ short Xs[128 * 128];
    __shared__ float sc[128];
    __shared__ float sh[128];
    const int b   = blockIdx.x;
    const int t   = threadIdx.x;
    const int w   = t >> 6;
    const int l15 = t & 15;
    const int l4  = (t >> 4) & 3;

    if (t < 128) {
        float sm = 0.f, sq = 0.f;
#pragma unroll 8
        for (int sl = 0; sl < NSLOT; ++sl) {
            sm += stats1[sl * 256 + t];
            sq += stats1[sl * 256 + 128 + t];
        }
        const float inv_n = 1.0f / (1024.0f * 128.0f);
        float m    = sm * inv_n;
        float var  = sq * inv_n - m * m;
        float rstd = rsqrtf(var + 1e-5f);
        float s    = rstd * g1[t];
        sc[t] = s;
        sh[t] = bt1[t] - m * s;
    }
    __syncthreads();

    {
        const int c8 = t & 15;
        const int eb = t >> 4;
#pragma unroll
        for (int p = 0; p < 8; ++p) {
            int e = eb + 16 * p;
            bf16x8 v8 = *(const bf16x8*)&h[((size_t)b * EE + e) * DD + c8 * 8];
            float s = sc[e], s0 = sh[e];
            bf16x8 o;
#pragma unroll
            for (int i = 0; i < 8; ++i)
                o[i] = f2bf(fmaxf(fmaf(bf2f(v8[i]), s, s0), 0.0f));
            *(bf16x8*)&Xs[e * 128 + ((c8 ^ (e & 7)) << 3)] = o;
        }
    }
    __syncthreads();

    f32x4 acc[8][2];
#pragma unroll
    for (int i = 0; i < 8; ++i) {
        acc[i][0] = f32x4{0.f, 0.f, 0.f, 0.f};
        acc[i][1] = f32x4{0.f, 0.f, 0.f, 0.f};
    }
#pragma unroll
    for (int kf = 0; kf < 4; ++kf) {
        const int k0 = kf * 32;
        const int cb = (k0 >> 3) + l4;
        bf16x8 af[8];
#pragma unroll
        for (int rf = 0; rf < 8; ++rf) {
            int row = rf * 16 + l15;
            af[rf] = *(const bf16x8*)&Xs[row * 128 + ((cb ^ (row & 7)) * 8)];
        }
#pragma unroll
        for (int cf = 0; cf < 2; ++cf) {
            int j = w * 32 + cf * 16 + l15;
            bf16x8 bfr = *(const bf16x8*)&W2b[(size_t)j * 128 + k0 + l4 * 8];
#pragma unroll
            for (int rf = 0; rf < 8; ++rf)
                acc[rf][cf] = __builtin_amdgcn_mfma_f32_16x16x32_bf16(af[rf], bfr, acc[rf][cf], 0, 0, 0);
        }
    }

    __syncthreads();
    float* red = (float*)Xs;
    const float bj0 = b2[w * 32 + l15];
    const float bj1 = b2[w * 32 + 16 + l15];
    const int j0 = w * 32 + l15;
#pragma unroll
    for (int rf = 0; rf < 8; ++rf) {
        f32x4 v0 = acc[rf][0] + bj0;
        f32x4 v1 = acc[rf][1] + bj1;
        int elb = rf * 16 + l4 * 4;
#pragma unroll
        for (int r = 0; r < 4; ++r) {
            unsigned short* op = h + (size_t)(b * EE + elb + r) * DD;
            op[j0]      = (unsigned short)f2bf(v0[r]);
            op[j0 + 16] = (unsigned short)f2bf(v1[r]);
            float s = v0[r] + v1[r];
            float q = v0[r] * v0[r] + v1[r] * v1[r];
            s += __shfl_xor(s, 1); s += __shfl_xor(s, 2); s += __shfl_xor(s, 4); s += __shfl_xor(s, 8);
            q += __shfl_xor(q, 1); q += __shfl_xor(q, 2); q += __shfl_xor(q, 4); q += __shfl_xor(q, 8);
            if (l15 == 0) {
                red[(elb + r) * 4 + w]       = s;
                red[512 + (elb + r) * 4 + w] = q;
            }
        }
    }
    __syncthreads();
    if (t < 128) {
        float s = red[t * 4] + red[t * 4 + 1] + red[t * 4 + 2] + red[t * 4 + 3];
        float q = red[512 + t * 4] + red[512 + t * 4 + 1] + red[512 + t * 4 + 2] + red[512 + t * 4 + 3];
        int slot = b & (NSLOT - 1);
        atomicAdd(&stats2[slot * 256 + t], s);
        atomicAdd(&stats2[slot * 256 + 128 + t], q);
    }
}

// K5: finalize BN2, out = relu(eout + h2*scale + shift); h2 is bf16.
__global__ __launch_bounds__(256)
void k5_final(const unsigned short* __restrict__ h2, const float* __restrict__ eout,
              const float* __restrict__ g2, const float* __restrict__ bt2,
              float* __restrict__ out, const float* __restrict__ stats2)
{
    __shared__ float sc[128];
    __shared__ float sh[128];
    const int t = threadIdx.x;
    if (t < 128) {
        float sm = 0.f, sq = 0.f;
#pragma unroll 8
        for (int sl = 0; sl < NSLOT; ++sl) {
            sm += stats2[sl * 256 + t];
            sq += stats2[sl * 256 + 128 + t];
        }
        const float inv_n = 1.0f / (1024.0f * 128.0f);
        float m    = sm * inv_n;
        float var  = sq * inv_n - m * m;
        float rstd = rsqrtf(var + 1e-5f);
        float s    = rstd * g2[t];
        sc[t] = s;
        sh[t] = bt2[t] - m * s;
    }
    __syncthreads();

    const int total8 = BB * EE * DD / 8;
    for (int i8 = blockIdx.x * blockDim.x + t; i8 < total8; i8 += gridDim.x * blockDim.x) {
        int e = (i8 >> 4) & 127;
        bf16x8 v8 = *(const bf16x8*)(h2 + (size_t)i8 * 8);
        f32x4 u0 = *(const f32x4*)(eout + (size_t)i8 * 8);
        f32x4 u1 = *(const f32x4*)(eout + (size_t)i8 * 8 + 4);
        float s = sc[e], s0 = sh[e];
        f32x4 o0, o1;
#pragma unroll
        for (int i = 0; i < 4; ++i) {
            o0[i] = fmaxf(u0[i] + fmaf(bf2f(v8[i]), s, s0), 0.0f);
            o1[i] = fmaxf(u1[i] + fmaf(bf2f(v8[i + 4]), s, s0), 0.0f);
        }
        *(f32x4*)(out + (size_t)i8 * 8)     = o0;
        *(f32x4*)(out + (size_t)i8 * 8 + 4) = o1;
    }
}

extern "C" void kernel_launch(void* const* d_in, const int* in_sizes, int n_in,
                              void* d_out, int out_size, void* d_ws, size_t ws_size,
                              hipStream_t stream)
{
    const float* gout  = (const float*)d_in[0];
    const float* eout  = (const float*)d_in[1];
    const float* ss    = (const float*)d_in[2];
    const float* es    = (const float*)d_in[3];
    const float* W1    = (const float*)d_in[4];
    const float* b1    = (const float*)d_in[5];
    const float* W2    = (const float*)d_in[6];
    const float* b2    = (const float*)d_in[7];
    const float* g1    = (const float*)d_in[8];
    const float* bt1   = (const float*)d_in[9];
    const float* g2    = (const float*)d_in[10];
    const float* bt2   = (const float*)d_in[11];

    float* stats1 = (float*)d_ws;                              // [64][256]
    float* stats2 = stats1 + NSLOT * 256;                      // [64][256]
    unsigned short* W1b = (unsigned short*)(stats2 + NSLOT * 256);  // 32768 bf16
    unsigned short* W2b = W1b + 32768;                         // 16384 bf16
    unsigned short* h   = W2b + 16384;                         // [B][E][D] bf16 (h, then h2 in-place)
    float* out    = (float*)d_out;

    hipMemsetAsync((void*)stats1, 0, 2 * NSLOT * 256 * sizeof(float), stream);
    k0_cvtw<<<dim3(128), dim3(256), 0, stream>>>(W1, W2, W1b, W2b);
    k1_gemm<<<dim3(2 * BB), dim3(512), 0, stream>>>(gout, ss, es, W1b, b1, h, stats1);
    k3_gemm<<<dim3(BB), dim3(256), 0, stream>>>(h, W2b, b2, g1, bt1, stats1, stats2);
    k5_final<<<dim3(2048), dim3(256), 0, stream>>>(h, eout, g2, bt2, out, stats2);
}

// Round 11
// 271.791 us; speedup vs baseline: 1.0362x; 1.0132x over previous
//
#include <hip/hip_runtime.h>
#include <stdint.h>

#define BB 1024
#define NN 400
#define EE 128
#define DD 128
#define NSLOT 64
#define GTS 424              // GT row stride in shorts (848B rows)

typedef float f32x4 __attribute__((ext_vector_type(4)));
typedef short bf16x8 __attribute__((ext_vector_type(8)));

__device__ __forceinline__ short f2bf(float f) {
    uint32_t u = __builtin_bit_cast(uint32_t, f);
    u += 0x7fffu + ((u >> 16) & 1u);
    return (short)(u >> 16);
}

__device__ __forceinline__ float bf2f(short s) {
    return __builtin_bit_cast(float, (uint32_t)((uint16_t)s) << 16);
}

__device__ __forceinline__ bf16x8 cvt8(const f32x4 a, const f32x4 b) {
    bf16x8 r;
    r[0] = f2bf(a[0]); r[1] = f2bf(a[1]); r[2] = f2bf(a[2]); r[3] = f2bf(a[3]);
    r[4] = f2bf(b[0]); r[5] = f2bf(b[1]); r[6] = f2bf(b[2]); r[7] = f2bf(b[3]);
    return r;
}

// K0: one-shot convert W1 (32768) and W2 (16384) to bf16 in workspace.
__global__ __launch_bounds__(256)
void k0_cvtw(const float* __restrict__ W1, const float* __restrict__ W2,
             unsigned short* __restrict__ W1b, unsigned short* __restrict__ W2b)
{
    int i = blockIdx.x * 256 + threadIdx.x;
    if (i < 32768) W1b[i] = (unsigned short)f2bf(W1[i]);
    if (i < 16384) W2b[i] = (unsigned short)f2bf(W2[i]);
}

// K1: one 1024-thread block per b (16 waves, 1 block/CU, LDS 106KB).
//   GT staging: BATCHED PRELOAD — 2 batches x (7 iters x 4 scalar loads into
//   static regs) then pack+b64-write; collapses 28 serial HBM round-trips to ~2.
//   K-loop (barrier-free): 2-deep raw-f32 A ring (cvt deferred 2 iters),
//   8 ds_read_b128 + 8 MFMA per wave-step, setprio around MFMA cluster.
//   Phase 2: P'->Ps[256][128] swizzled (aliases GT); h = X @ W1b^T + b1
//   (W1b bf16 from L2); h bf16 store + BN1 slot stats.
__global__ __launch_bounds__(1024, 1)
void k1_gemm(const float* __restrict__ gout, const float* __restrict__ ss,
             const float* __restrict__ es, const unsigned short* __restrict__ W1b,
             const float* __restrict__ b1, unsigned short* __restrict__ h,
             float* __restrict__ stats1)
{
    __shared__ short lds[54272];           // 106 KB
    short* GT = lds;                       // [128][424] bf16, phases 0/1
    short* Ps = lds;                       // [256][128] bf16, phase 2 (aliases GT)

    const int b   = blockIdx.x;
    const int t   = threadIdx.x;
    const int w   = t >> 6;                // wave 0..15
    const int l   = t & 63;
    const int l15 = l & 15;
    const int l4  = l >> 4;                // 0..3
    const int kkoff = l4 * 8;

    // ---- pre-issue A ring for K-steps 0,1 (raw f32; cvt deferred) ----
    const int arow = (w & 7) * 16 + l15;
    const float* abase = ((w < 8) ? ss : es) + ((size_t)b * EE + arow) * NN;

    f32x4 pa0 = *(const f32x4*)(abase + kkoff);
    f32x4 pa1 = *(const f32x4*)(abase + kkoff + 4);
    f32x4 pb0 = *(const f32x4*)(abase + 32 + kkoff);
    f32x4 pb1 = *(const f32x4*)(abase + 32 + kkoff + 4);

    // ---- GT staging: batched preload then pack+write ----
    {
        const float* gb = gout + (size_t)b * NN * DD + (t & 127);
        const int qb = t >> 7;             // 0..7 (quads strided by 8)
        short* grow = &GT[(t & 127) * GTS];
#pragma unroll
        for (int half = 0; half < 2; ++half) {
            float v[7][4];
#pragma unroll
            for (int i = 0; i < 7; ++i) {
                int q  = qb + 8 * (half * 7 + i);
                int kg = 4 * q;
                v[i][0] = (kg     < NN) ? gb[(size_t)(kg)     * DD] : 0.f;
                v[i][1] = (kg + 1 < NN) ? gb[(size_t)(kg + 1) * DD] : 0.f;
                v[i][2] = (kg + 2 < NN) ? gb[(size_t)(kg + 2) * DD] : 0.f;
                v[i][3] = (kg + 3 < NN) ? gb[(size_t)(kg + 3) * DD] : 0.f;
            }
#pragma unroll
            for (int i = 0; i < 7; ++i) {
                int q = qb + 8 * (half * 7 + i);
                if (q < 106) {
                    uint32_t lo = (uint32_t)(uint16_t)f2bf(v[i][0]) |
                                  ((uint32_t)(uint16_t)f2bf(v[i][1]) << 16);
                    uint32_t hi = (uint32_t)(uint16_t)f2bf(v[i][2]) |
                                  ((uint32_t)(uint16_t)f2bf(v[i][3]) << 16);
                    *(uint64_t*)&grow[4 * q] = ((uint64_t)hi << 32) | lo;
                }
            }
        }
    }
    __syncthreads();

    // ---- K-loop: P(16 rows x 128 d per wave), barrier-free ----
    f32x4 acc[8];
#pragma unroll
    for (int cf = 0; cf < 8; ++cf) acc[cf] = f32x4{0.f, 0.f, 0.f, 0.f};

#pragma unroll
    for (int s = 0; s < 13; ++s) {
        bf16x8 a = cvt8(pa0, pa1);         // loads from 2 iterations ago
        pa0 = pb0; pa1 = pb1;
        const int sn = s + 2;
        if (sn < 12) {
            pb0 = *(const f32x4*)(abase + sn * 32 + kkoff);
            pb1 = *(const f32x4*)(abase + sn * 32 + kkoff + 4);
        } else if (sn == 12) {
            int kk = 384 + kkoff;
            pb0 = f32x4{0.f, 0.f, 0.f, 0.f};
            pb1 = f32x4{0.f, 0.f, 0.f, 0.f};
            if (kk < NN)     pb0 = *(const f32x4*)(abase + kk);
            if (kk + 4 < NN) pb1 = *(const f32x4*)(abase + kk + 4);
        }
        const int k0 = s * 32 + kkoff;
        __builtin_amdgcn_s_setprio(1);
#pragma unroll
        for (int cf = 0; cf < 8; ++cf) {
            bf16x8 gf = *(const bf16x8*)&GT[(cf * 16 + l15) * GTS + k0];
            acc[cf] = __builtin_amdgcn_mfma_f32_16x16x32_bf16(a, gf, acc[cf], 0, 0, 0);
        }
        __builtin_amdgcn_s_setprio(0);
    }
    __syncthreads();                       // GT dead; Ps live

    // ---- phase 2a: write P' swizzled into Ps[256][128] ----
#pragma unroll
    for (int cf = 0; cf < 8; ++cf)
#pragma unroll
        for (int r = 0; r < 4; ++r) {
            int row = w * 16 + l4 * 4 + r;         // 0..255 (S rows, then T rows)
            int col = cf * 16 + l15;
            Ps[row * 128 + (((col >> 3) ^ (row & 7)) << 3) + (col & 7)] = f2bf(acc[cf][r]);
        }
    __syncthreads();

    // ---- phase 2b: h(16 e-rows x 64 j per wave) = X @ W1^T (W1b from L2) ----
    const int mt = w >> 1;                 // 0..7
    const int jh = w & 1;
    f32x4 acc2[4];
#pragma unroll
    for (int cf = 0; cf < 4; ++cf) acc2[cf] = f32x4{0.f, 0.f, 0.f, 0.f};

#pragma unroll
    for (int kf = 0; kf < 8; ++kf) {
        int roff = (kf >= 4) ? 128 : 0;
        int row  = roff + mt * 16 + l15;
        int cb   = (kf & 3) * 4 + l4;
        bf16x8 xf = *(const bf16x8*)&Ps[row * 128 + ((cb ^ (row & 7)) << 3)];
#pragma unroll
        for (int cf = 0; cf < 4; ++cf) {
            int j = jh * 64 + cf * 16 + l15;
            bf16x8 wf = *(const bf16x8*)&W1b[(size_t)j * 256 + kf * 32 + l4 * 8];
            acc2[cf] = __builtin_amdgcn_mfma_f32_16x16x32_bf16(xf, wf, acc2[cf], 0, 0, 0);
        }
    }
    __syncthreads();                       // Ps dead; red live

    // ---- phase 2c: bias, store h (bf16), BN1 stats ----
    float* red = (float*)lds;
    float s_r[4] = {0.f, 0.f, 0.f, 0.f};
    float q_r[4] = {0.f, 0.f, 0.f, 0.f};
#pragma unroll
    for (int cf = 0; cf < 4; ++cf) {
        float bv = b1[jh * 64 + cf * 16 + l15];
        f32x4 v = acc2[cf] + bv;
#pragma unroll
        for (int r = 0; r < 4; ++r) {
            int e = mt * 16 + l4 * 4 + r;
            h[((size_t)b * EE + e) * DD + jh * 64 + cf * 16 + l15] = (unsigned short)f2bf(v[r]);
            s_r[r] += v[r];
            q_r[r] += v[r] * v[r];
        }
    }
#pragma unroll
    for (int r = 0; r < 4; ++r) {
        float s = s_r[r], q = q_r[r];
        s += __shfl_xor(s, 1); s += __shfl_xor(s, 2); s += __shfl_xor(s, 4); s += __shfl_xor(s, 8);
        q += __shfl_xor(q, 1); q += __shfl_xor(q, 2); q += __shfl_xor(q, 4); q += __shfl_xor(q, 8);
        if (l15 == 0) {
            int e = mt * 16 + l4 * 4 + r;
            red[(e << 1) | jh]         = s;
            red[256 + ((e << 1) | jh)] = q;
        }
    }
    __syncthreads();
    if (t < 128) {
        float s = red[2 * t] + red[2 * t + 1];
        float q = red[256 + 2 * t] + red[256 + 2 * t + 1];
        int slot = b & (NSLOT - 1);
        atomicAdd(&stats1[slot * 256 + t], s);
        atomicAdd(&stats1[slot * 256 + 128 + t], q);
    }
}

// K3: per b: finalize BN1, normalize+relu h(bf16) -> bf16 LDS,
// h2 = X @ W2b^T + b2 -> IN-PLACE over h (bf16), BN2 stats.
__global__ __launch_bounds__(256, 4)
void k3_gemm(unsigned short* h, const unsigned short* __restrict__ W2b,
             const float* __restrict__ b2, const float* __restrict__ g1,
             const float* __restrict__ bt1,
             const float* __restrict__ stats1, float* __restrict__ stats2)
{
    __shared__ short Xs[128 * 128];
    __shared__ float sc[128];
    __shared__ float sh[128];
    const int b   = blockIdx.x;
    const int t   = threadIdx.x;
    const int w   = t >> 6;
    const int l15 = t & 15;
    const int l4  = (t >> 4) & 3;

    if (t < 128) {
        float sm = 0.f, sq = 0.f;
#pragma unroll 8
        for (int sl = 0; sl < NSLOT; ++sl) {
            sm += stats1[sl * 256 + t];
            sq += stats1[sl * 256 + 128 + t];
        }
        const float inv_n = 1.0f / (1024.0f * 128.0f);
        float m    = sm * inv_n;
        float var  = sq * inv_n - m * m;
        float rstd = rsqrtf(var + 1e-5f);
        float s    = rstd * g1[t];
        sc[t] = s;
        sh[t] = bt1[t] - m * s;
    }
    __syncthreads();

    {
        const int c8 = t & 15;
        const int eb = t >> 4;
#pragma unroll
        for (int p = 0; p < 8; ++p) {
            int e = eb + 16 * p;
            bf16x8 v8 = *(const bf16x8*)&h[((size_t)b * EE + e) * DD + c8 * 8];
            float s = sc[e], s0 = sh[e];
            bf16x8 o;
#pragma unroll
            for (int i = 0; i < 8; ++i)
                o[i] = f2bf(fmaxf(fmaf(bf2f(v8[i]), s, s0), 0.0f));
            *(bf16x8*)&Xs[e * 128 + ((c8 ^ (e & 7)) << 3)] = o;
        }
    }
    __syncthreads();

    f32x4 acc[8][2];
#pragma unroll
    for (int i = 0; i < 8; ++i) {
        acc[i][0] = f32x4{0.f, 0.f, 0.f, 0.f};
        acc[i][1] = f32x4{0.f, 0.f, 0.f, 0.f};
    }
#pragma unroll
    for (int kf = 0; kf < 4; ++kf) {
        const int k0 = kf * 32;
        const int cb = (k0 >> 3) + l4;
        bf16x8 af[8];
#pragma unroll
        for (int rf = 0; rf < 8; ++rf) {
            int row = rf * 16 + l15;
            af[rf] = *(const bf16x8*)&Xs[row * 128 + ((cb ^ (row & 7)) * 8)];
        }
#pragma unroll
        for (int cf = 0; cf < 2; ++cf) {
            int j = w * 32 + cf * 16 + l15;
            bf16x8 bfr = *(const bf16x8*)&W2b[(size_t)j * 128 + k0 + l4 * 8];
#pragma unroll
            for (int rf = 0; rf < 8; ++rf)
                acc[rf][cf] = __builtin_amdgcn_mfma_f32_16x16x32_bf16(af[rf], bfr, acc[rf][cf], 0, 0, 0);
        }
    }

    __syncthreads();
    float* red = (float*)Xs;
    const float bj0 = b2[w * 32 + l15];
    const float bj1 = b2[w * 32 + 16 + l15];
    const int j0 = w * 32 + l15;
#pragma unroll
    for (int rf = 0; rf < 8; ++rf) {
        f32x4 v0 = acc[rf][0] + bj0;
        f32x4 v1 = acc[rf][1] + bj1;
        int elb = rf * 16 + l4 * 4;
#pragma unroll
        for (int r = 0; r < 4; ++r) {
            unsigned short* op = h + (size_t)(b * EE + elb + r) * DD;
            op[j0]      = (unsigned short)f2bf(v0[r]);
            op[j0 + 16] = (unsigned short)f2bf(v1[r]);
            float s = v0[r] + v1[r];
            float q = v0[r] * v0[r] + v1[r] * v1[r];
            s += __shfl_xor(s, 1); s += __shfl_xor(s, 2); s += __shfl_xor(s, 4); s += __shfl_xor(s, 8);
            q += __shfl_xor(q, 1); q += __shfl_xor(q, 2); q += __shfl_xor(q, 4); q += __shfl_xor(q, 8);
            if (l15 == 0) {
                red[(elb + r) * 4 + w]       = s;
                red[512 + (elb + r) * 4 + w] = q;
            }
        }
    }
    __syncthreads();
    if (t < 128) {
        float s = red[t * 4] + red[t * 4 + 1] + red[t * 4 + 2] + red[t * 4 + 3];
        float q = red[512 + t * 4] + red[512 + t * 4 + 1] + red[512 + t * 4 + 2] + red[512 + t * 4 + 3];
        int slot = b & (NSLOT - 1);
        atomicAdd(&stats2[slot * 256 + t], s);
        atomicAdd(&stats2[slot * 256 + 128 + t], q);
    }
}

// K5: finalize BN2, out = relu(eout + h2*scale + shift); h2 is bf16.
__global__ __launch_bounds__(256)
void k5_final(const unsigned short* __restrict__ h2, const float* __restrict__ eout,
              const float* __restrict__ g2, const float* __restrict__ bt2,
              float* __restrict__ out, const float* __restrict__ stats2)
{
    __shared__ float sc[128];
    __shared__ float sh[128];
    const int t = threadIdx.x;
    if (t < 128) {
        float sm = 0.f, sq = 0.f;
#pragma unroll 8
        for (int sl = 0; sl < NSLOT; ++sl) {
            sm += stats2[sl * 256 + t];
            sq += stats2[sl * 256 + 128 + t];
        }
        const float inv_n = 1.0f / (1024.0f * 128.0f);
        float m    = sm * inv_n;
        float var  = sq * inv_n - m * m;
        float rstd = rsqrtf(var + 1e-5f);
        float s    = rstd * g2[t];
        sc[t] = s;
        sh[t] = bt2[t] - m * s;
    }
    __syncthreads();

    const int total8 = BB * EE * DD / 8;
    for (int i8 = blockIdx.x * blockDim.x + t; i8 < total8; i8 += gridDim.x * blockDim.x) {
        int e = (i8 >> 4) & 127;
        bf16x8 v8 = *(const bf16x8*)(h2 + (size_t)i8 * 8);
        f32x4 u0 = *(const f32x4*)(eout + (size_t)i8 * 8);
        f32x4 u1 = *(const f32x4*)(eout + (size_t)i8 * 8 + 4);
        float s = sc[e], s0 = sh[e];
        f32x4 o0, o1;
#pragma unroll
        for (int i = 0; i < 4; ++i) {
            o0[i] = fmaxf(u0[i] + fmaf(bf2f(v8[i]), s, s0), 0.0f);
            o1[i] = fmaxf(u1[i] + fmaf(bf2f(v8[i + 4]), s, s0), 0.0f);
        }
        *(f32x4*)(out + (size_t)i8 * 8)     = o0;
        *(f32x4*)(out + (size_t)i8 * 8 + 4) = o1;
    }
}

extern "C" void kernel_launch(void* const* d_in, const int* in_sizes, int n_in,
                              void* d_out, int out_size, void* d_ws, size_t ws_size,
                              hipStream_t stream)
{
    const float* gout  = (const float*)d_in[0];
    const float* eout  = (const float*)d_in[1];
    const float* ss    = (const float*)d_in[2];
    const float* es    = (const float*)d_in[3];
    const float* W1    = (const float*)d_in[4];
    const float* b1    = (const float*)d_in[5];
    const float* W2    = (const float*)d_in[6];
    const float* b2    = (const float*)d_in[7];
    const float* g1    = (const float*)d_in[8];
    const float* bt1   = (const float*)d_in[9];
    const float* g2    = (const float*)d_in[10];
    const float* bt2   = (const float*)d_in[11];

    float* stats1 = (float*)d_ws;                              // [64][256]
    float* stats2 = stats1 + NSLOT * 256;                      // [64][256]
    unsigned short* W1b = (unsigned short*)(stats2 + NSLOT * 256);  // 32768 bf16
    unsigned short* W2b = W1b + 32768;                         // 16384 bf16
    unsigned short* h   = W2b + 16384;                         // [B][E][D] bf16 (h, then h2 in-place)
    float* out    = (float*)d_out;

    hipMemsetAsync((void*)stats1, 0, 2 * NSLOT * 256 * sizeof(float), stream);
    k0_cvtw<<<dim3(128), dim3(256), 0, stream>>>(W1, W2, W1b, W2b);
    k1_gemm<<<dim3(BB), dim3(1024), 0, stream>>>(gout, ss, es, W1b, b1, h, stats1);
    k3_gemm<<<dim3(BB), dim3(256), 0, stream>>>(h, W2b, b2, g1, bt1, stats1, stats2);
    k5_final<<<dim3(2048), dim3(256), 0, stream>>>(h, eout, g2, bt2, out, stats2);
}

// Round 12
// 261.197 us; speedup vs baseline: 1.0782x; 1.0406x over previous
//
#include <hip/hip_runtime.h>
#include <stdint.h>

#define BB 1024
#define NN 400
#define EE 128
#define DD 128
#define NSLOT 64
#define GTS 424              // GT row stride in shorts (848B rows, 16B-aligned)

typedef float f32x4 __attribute__((ext_vector_type(4)));
typedef float f32x2 __attribute__((ext_vector_type(2)));
typedef short bf16x8 __attribute__((ext_vector_type(8)));

__device__ __forceinline__ short f2bf(float f) {
    uint32_t u = __builtin_bit_cast(uint32_t, f);
    u += 0x7fffu + ((u >> 16) & 1u);
    return (short)(u >> 16);
}

__device__ __forceinline__ float bf2f(short s) {
    return __builtin_bit_cast(float, (uint32_t)((uint16_t)s) << 16);
}

__device__ __forceinline__ bf16x8 cvt8(const f32x4 a, const f32x4 b) {
    bf16x8 r;
    r[0] = f2bf(a[0]); r[1] = f2bf(a[1]); r[2] = f2bf(a[2]); r[3] = f2bf(a[3]);
    r[4] = f2bf(b[0]); r[5] = f2bf(b[1]); r[6] = f2bf(b[2]); r[7] = f2bf(b[3]);
    return r;
}

// K0: one-shot convert W1 (32768) and W2 (16384) to bf16 in workspace.
__global__ __launch_bounds__(256)
void k0_cvtw(const float* __restrict__ W1, const float* __restrict__ W2,
             unsigned short* __restrict__ W1b, unsigned short* __restrict__ W2b)
{
    int i = blockIdx.x * 256 + threadIdx.x;
    if (i < 32768) W1b[i] = (unsigned short)f2bf(W1[i]);
    if (i < 16384) W2b[i] = (unsigned short)f2bf(W2[i]);
}

// K1a: PURE stage-1 GEMM. One 1024-thread block per b.
//   GT staging: f32x2-pair loads (26 8B loads/thread vs 50 scalar), packing
//   k-pairs to b32 writes with 2-bit chunk-XOR ((d>>2)&3) swizzle; chunks
//   holding k>=400 zero-filled with b128 stores.
//   K-loop: ROLLED (#pragma unroll 1) — one clean pipelined iteration body;
//   2-deep raw-f32 A ring, 8 ds_read_b128 (chunk-XOR) + 8 MFMA per step.
//   Epilogue: P' -> LDS swizzled; linear b128 stream-out of the 64KB image.
__global__ __launch_bounds__(1024, 1)
void k1a_gemm(const float* __restrict__ gout, const float* __restrict__ ss,
              const float* __restrict__ es, unsigned short* __restrict__ Pg)
{
    __shared__ short lds[54272];           // 106 KB
    short* GT = lds;                       // [128][424] bf16, chunk-XOR swizzled
    short* Pl = lds;                       // [256][128] bf16 swizzled (aliases GT)

    const int b   = blockIdx.x;
    const int t   = threadIdx.x;
    const int w   = t >> 6;                // wave 0..15
    const int l   = t & 63;
    const int l15 = l & 15;
    const int l4  = l >> 4;                // 0..3
    const int kkoff = l4 * 8;

    // pre-issue A ring for K-steps 0,1 (raw f32; cvt deferred 2 iters)
    const int arow = (w & 7) * 16 + l15;
    const float* abase = ((w < 8) ? ss : es) + ((size_t)b * EE + arow) * NN;

    f32x4 pa0 = *(const f32x4*)(abase + kkoff);
    f32x4 pa1 = *(const f32x4*)(abase + kkoff + 4);
    f32x4 pb0 = *(const f32x4*)(abase + 32 + kkoff);
    f32x4 pb1 = *(const f32x4*)(abase + 32 + kkoff + 4);

    // ---- GT staging: f32x2 pairs along d, k-pairs packed to b32 ----
    {
        const float* gb = gout + (size_t)b * NN * DD;
        const int d0  = 2 * (t & 63);      // even d
        const int kp0 = t >> 6;            // k-pair base 0..15
        const int xsw = (d0 >> 2) & 3;     // same for d0 and d0+1
        for (int kp = kp0; kp < 200; kp += 16) {
            int k = 2 * kp;
            f32x2 g0 = *(const f32x2*)(gb + (size_t)k * DD + d0);
            f32x2 g1 = *(const f32x2*)(gb + (size_t)(k + 1) * DD + d0);
            uint32_t lo = (uint32_t)(uint16_t)f2bf(g0[0]) | ((uint32_t)(uint16_t)f2bf(g1[0]) << 16);
            uint32_t hi = (uint32_t)(uint16_t)f2bf(g0[1]) | ((uint32_t)(uint16_t)f2bf(g1[1]) << 16);
            int sc  = (kp >> 2) ^ xsw;     // stored chunk
            int off = (sc << 3) + 2 * (kp & 3);
            *(uint32_t*)&GT[d0 * GTS + off]       = lo;
            *(uint32_t*)&GT[(d0 + 1) * GTS + off] = hi;
        }
        // zero-fill stored slots holding real k-chunks 50,51 (k 400..415)
        if (t < 256) {
            int d  = t & 127;
            int rc = 50 + ((t >> 7) & 1);
            int sc = rc ^ ((d >> 2) & 3);
            bf16x8 z = {0, 0, 0, 0, 0, 0, 0, 0};
            *(bf16x8*)&GT[d * GTS + sc * 8] = z;
        }
    }
    __syncthreads();

    // ---- K-loop: P(16 rows x 128 d per wave), ROLLED, barrier-free ----
    f32x4 acc[8];
#pragma unroll
    for (int cf = 0; cf < 8; ++cf) acc[cf] = f32x4{0.f, 0.f, 0.f, 0.f};

    const int xr = (l15 >> 2) & 3;         // read-side chunk XOR (col>>2)&3, cf-independent
#pragma unroll 1
    for (int s = 0; s < 13; ++s) {
        bf16x8 a = cvt8(pa0, pa1);         // loads from 2 iterations ago
        pa0 = pb0; pa1 = pb1;
        const int sn = s + 2;
        if (sn < 12) {
            pb0 = *(const f32x4*)(abase + sn * 32 + kkoff);
            pb1 = *(const f32x4*)(abase + sn * 32 + kkoff + 4);
        } else if (sn == 12) {
            int kk = 384 + kkoff;
            pb0 = f32x4{0.f, 0.f, 0.f, 0.f};
            pb1 = f32x4{0.f, 0.f, 0.f, 0.f};
            if (kk < NN)     pb0 = *(const f32x4*)(abase + kk);
            if (kk + 4 < NN) pb1 = *(const f32x4*)(abase + kk + 4);
        }
        const int cc = 4 * s + l4;         // real k-chunk this lane reads
#pragma unroll
        for (int cf = 0; cf < 8; ++cf) {
            int col = cf * 16 + l15;
            bf16x8 gf = *(const bf16x8*)&GT[col * GTS + ((cc ^ xr) << 3)];
            acc[cf] = __builtin_amdgcn_mfma_f32_16x16x32_bf16(a, gf, acc[cf], 0, 0, 0);
        }
    }
    __syncthreads();                       // GT dead; Pl live

    // P' -> Pl swizzled: elem(row,col) at row*128 + ((col>>3 ^ row&7)<<3) + col&7
#pragma unroll
    for (int cf = 0; cf < 8; ++cf)
#pragma unroll
        for (int r = 0; r < 4; ++r) {
            int row = w * 16 + l4 * 4 + r;         // 0..255 (S rows, then T rows)
            int col = cf * 16 + l15;
            Pl[row * 128 + (((col >> 3) ^ (row & 7)) << 3) + (col & 7)] = f2bf(acc[cf][r]);
        }
    __syncthreads();

    // stream the 64KB swizzled image out linearly (b128, fully coalesced)
    unsigned short* pg = Pg + (size_t)b * 32768;
#pragma unroll
    for (int i = 0; i < 4; ++i) {
        int idx = i * 1024 + t;                    // 16B-chunk id, 4096 total
        bf16x8 v = *(const bf16x8*)&lds[idx * 8];
        *(bf16x8*)&pg[idx * 8] = v;
    }
}

// K1b: per b: copy P[b] (64KB swizzled image) into LDS linearly,
// h = X @ W1b^T + b1, write h bf16, BN1 slot stats.
__global__ __launch_bounds__(256, 2)
void k1b_stage2(const unsigned short* __restrict__ Pg,
                const unsigned short* __restrict__ W1b,
                const float* __restrict__ b1, unsigned short* __restrict__ h,
                float* __restrict__ stats1)
{
    __shared__ short Ps[32768];            // 64KB
    const int b   = blockIdx.x;
    const int t   = threadIdx.x;
    const int w   = t >> 6;
    const int l15 = t & 15;
    const int l4  = (t >> 4) & 3;

    const unsigned short* pg = Pg + (size_t)b * 32768;
#pragma unroll
    for (int i = 0; i < 16; ++i) {
        int idx = i * 256 + t;
        bf16x8 v = *(const bf16x8*)&pg[idx * 8];
        *(bf16x8*)&Ps[idx * 8] = v;
    }
    __syncthreads();

    f32x4 acc[8][2];
#pragma unroll
    for (int i = 0; i < 8; ++i) {
        acc[i][0] = f32x4{0.f, 0.f, 0.f, 0.f};
        acc[i][1] = f32x4{0.f, 0.f, 0.f, 0.f};
    }
#pragma unroll
    for (int kf = 0; kf < 8; ++kf) {
        const int roff = (kf >= 4) ? 128 : 0;
        const int cb   = (kf & 3) * 4 + l4;
        bf16x8 af[8];
#pragma unroll
        for (int rf = 0; rf < 8; ++rf) {
            int row = roff + rf * 16 + l15;
            af[rf] = *(const bf16x8*)&Ps[row * 128 + ((cb ^ (row & 7)) << 3)];
        }
#pragma unroll
        for (int cf = 0; cf < 2; ++cf) {
            int j = w * 32 + cf * 16 + l15;
            bf16x8 wf = *(const bf16x8*)&W1b[(size_t)j * 256 + kf * 32 + l4 * 8];
#pragma unroll
            for (int rf = 0; rf < 8; ++rf)
                acc[rf][cf] = __builtin_amdgcn_mfma_f32_16x16x32_bf16(af[rf], wf, acc[rf][cf], 0, 0, 0);
        }
    }

    __syncthreads();
    float* red = (float*)Ps;
    const float bj0 = b1[w * 32 + l15];
    const float bj1 = b1[w * 32 + 16 + l15];
    const int j0 = w * 32 + l15;
#pragma unroll
    for (int rf = 0; rf < 8; ++rf) {
        f32x4 v0 = acc[rf][0] + bj0;
        f32x4 v1 = acc[rf][1] + bj1;
        int elb = rf * 16 + l4 * 4;
#pragma unroll
        for (int r = 0; r < 4; ++r) {
            unsigned short* hp = h + (size_t)(b * EE + elb + r) * DD;
            hp[j0]      = (unsigned short)f2bf(v0[r]);
            hp[j0 + 16] = (unsigned short)f2bf(v1[r]);
            float s = v0[r] + v1[r];
            float q = v0[r] * v0[r] + v1[r] * v1[r];
            s += __shfl_xor(s, 1); s += __shfl_xor(s, 2); s += __shfl_xor(s, 4); s += __shfl_xor(s, 8);
            q += __shfl_xor(q, 1); q += __shfl_xor(q, 2); q += __shfl_xor(q, 4); q += __shfl_xor(q, 8);
            if (l15 == 0) {
                red[(elb + r) * 4 + w]       = s;
                red[512 + (elb + r) * 4 + w] = q;
            }
        }
    }
    __syncthreads();
    if (t < 128) {
        float s = red[t * 4] + red[t * 4 + 1] + red[t * 4 + 2] + red[t * 4 + 3];
        float q = red[512 + t * 4] + red[512 + t * 4 + 1] + red[512 + t * 4 + 2] + red[512 + t * 4 + 3];
        int slot = b & (NSLOT - 1);
        atomicAdd(&stats1[slot * 256 + t], s);
        atomicAdd(&stats1[slot * 256 + 128 + t], q);
    }
}

// K3: per b: finalize BN1, normalize+relu h(bf16) -> bf16 LDS,
// h2 = X @ W2b^T + b2 -> IN-PLACE over h (bf16), BN2 stats.
__global__ __launch_bounds__(256, 4)
void k3_gemm(unsigned short* h, const unsigned short* __restrict__ W2b,
             const float* __restrict__ b2, const float* __restrict__ g1,
             const float* __restrict__ bt1,
             const float* __restrict__ stats1, float* __restrict__ stats2)
{
    __shared__ short Xs[128 * 128];
    __shared__ float sc[128];
    __shared__ float sh[128];
    const int b   = blockIdx.x;
    const int t   = threadIdx.x;
    const int w   = t >> 6;
    const int l15 = t & 15;
    const int l4  = (t >> 4) & 3;

    if (t < 128) {
        float sm = 0.f, sq = 0.f;
#pragma unroll 8
        for (int sl = 0; sl < NSLOT; ++sl) {
            sm += stats1[sl * 256 + t];
            sq += stats1[sl * 256 + 128 + t];
        }
        const float inv_n = 1.0f / (1024.0f * 128.0f);
        float m    = sm * inv_n;
        float var  = sq * inv_n - m * m;
        float rstd = rsqrtf(var + 1e-5f);
        float s    = rstd * g1[t];
        sc[t] = s;
        sh[t] = bt1[t] - m * s;
    }
    __syncthreads();

    {
        const int c8 = t & 15;
        const int eb = t >> 4;
#pragma unroll
        for (int p = 0; p < 8; ++p) {
            int e = eb + 16 * p;
            bf16x8 v8 = *(const bf16x8*)&h[((size_t)b * EE + e) * DD + c8 * 8];
            float s = sc[e], s0 = sh[e];
            bf16x8 o;
#pragma unroll
            for (int i = 0; i < 8; ++i)
                o[i] = f2bf(fmaxf(fmaf(bf2f(v8[i]), s, s0), 0.0f));
            *(bf16x8*)&Xs[e * 128 + ((c8 ^ (e & 7)) << 3)] = o;
        }
    }
    __syncthreads();

    f32x4 acc[8][2];
#pragma unroll
    for (int i = 0; i < 8; ++i) {
        acc[i][0] = f32x4{0.f, 0.f, 0.f, 0.f};
        acc[i][1] = f32x4{0.f, 0.f, 0.f, 0.f};
    }
#pragma unroll
    for (int kf = 0; kf < 4; ++kf) {
        const int k0 = kf * 32;
        const int cb = (k0 >> 3) + l4;
        bf16x8 af[8];
#pragma unroll
        for (int rf = 0; rf < 8; ++rf) {
            int row = rf * 16 + l15;
            af[rf] = *(const bf16x8*)&Xs[row * 128 + ((cb ^ (row & 7)) * 8)];
        }
#pragma unroll
        for (int cf = 0; cf < 2; ++cf) {
            int j = w * 32 + cf * 16 + l15;
            bf16x8 bfr = *(const bf16x8*)&W2b[(size_t)j * 128 + k0 + l4 * 8];
#pragma unroll
            for (int rf = 0; rf < 8; ++rf)
                acc[rf][cf] = __builtin_amdgcn_mfma_f32_16x16x32_bf16(af[rf], bfr, acc[rf][cf], 0, 0, 0);
        }
    }

    __syncthreads();
    float* red = (float*)Xs;
    const float bj0 = b2[w * 32 + l15];
    const float bj1 = b2[w * 32 + 16 + l15];
    const int j0 = w * 32 + l15;
#pragma unroll
    for (int rf = 0; rf < 8; ++rf) {
        f32x4 v0 = acc[rf][0] + bj0;
        f32x4 v1 = acc[rf][1] + bj1;
        int elb = rf * 16 + l4 * 4;
#pragma unroll
        for (int r = 0; r < 4; ++r) {
            unsigned short* op = h + (size_t)(b * EE + elb + r) * DD;
            op[j0]      = (unsigned short)f2bf(v0[r]);
            op[j0 + 16] = (unsigned short)f2bf(v1[r]);
            float s = v0[r] + v1[r];
            float q = v0[r] * v0[r] + v1[r] * v1[r];
            s += __shfl_xor(s, 1); s += __shfl_xor(s, 2); s += __shfl_xor(s, 4); s += __shfl_xor(s, 8);
            q += __shfl_xor(q, 1); q += __shfl_xor(q, 2); q += __shfl_xor(q, 4); q += __shfl_xor(q, 8);
            if (l15 == 0) {
                red[(elb + r) * 4 + w]       = s;
                red[512 + (elb + r) * 4 + w] = q;
            }
        }
    }
    __syncthreads();
    if (t < 128) {
        float s = red[t * 4] + red[t * 4 + 1] + red[t * 4 + 2] + red[t * 4 + 3];
        float q = red[512 + t * 4] + red[512 + t * 4 + 1] + red[512 + t * 4 + 2] + red[512 + t * 4 + 3];
        int slot = b & (NSLOT - 1);
        atomicAdd(&stats2[slot * 256 + t], s);
        atomicAdd(&stats2[slot * 256 + 128 + t], q);
    }
}

// K5: finalize BN2, out = relu(eout + h2*scale + shift); h2 is bf16.
__global__ __launch_bounds__(256)
void k5_final(const unsigned short* __restrict__ h2, const float* __restrict__ eout,
              const float* __restrict__ g2, const float* __restrict__ bt2,
              float* __restrict__ out, const float* __restrict__ stats2)
{
    __shared__ float sc[128];
    __shared__ float sh[128];
    const int t = threadIdx.x;
    if (t < 128) {
        float sm = 0.f, sq = 0.f;
#pragma unroll 8
        for (int sl = 0; sl < NSLOT; ++sl) {
            sm += stats2[sl * 256 + t];
            sq += stats2[sl * 256 + 128 + t];
        }
        const float inv_n = 1.0f / (1024.0f * 128.0f);
        float m    = sm * inv_n;
        float var  = sq * inv_n - m * m;
        float rstd = rsqrtf(var + 1e-5f);
        float s    = rstd * g2[t];
        sc[t] = s;
        sh[t] = bt2[t] - m * s;
    }
    __syncthreads();

    const int total8 = BB * EE * DD / 8;
    for (int i8 = blockIdx.x * blockDim.x + t; i8 < total8; i8 += gridDim.x * blockDim.x) {
        int e = (i8 >> 4) & 127;
        bf16x8 v8 = *(const bf16x8*)(h2 + (size_t)i8 * 8);
        f32x4 u0 = *(const f32x4*)(eout + (size_t)i8 * 8);
        f32x4 u1 = *(const f32x4*)(eout + (size_t)i8 * 8 + 4);
        float s = sc[e], s0 = sh[e];
        f32x4 o0, o1;
#pragma unroll
        for (int i = 0; i < 4; ++i) {
            o0[i] = fmaxf(u0[i] + fmaf(bf2f(v8[i]), s, s0), 0.0f);
            o1[i] = fmaxf(u1[i] + fmaf(bf2f(v8[i + 4]), s, s0), 0.0f);
        }
        *(f32x4*)(out + (size_t)i8 * 8)     = o0;
        *(f32x4*)(out + (size_t)i8 * 8 + 4) = o1;
    }
}

extern "C" void kernel_launch(void* const* d_in, const int* in_sizes, int n_in,
                              void* d_out, int out_size, void* d_ws, size_t ws_size,
                              hipStream_t stream)
{
    const float* gout  = (const float*)d_in[0];
    const float* eout  = (const float*)d_in[1];
    const float* ss    = (const float*)d_in[2];
    const float* es    = (const float*)d_in[3];
    const float* W1    = (const float*)d_in[4];
    const float* b1    = (const float*)d_in[5];
    const float* W2    = (const float*)d_in[6];
    const float* b2    = (const float*)d_in[7];
    const float* g1    = (const float*)d_in[8];
    const float* bt1   = (const float*)d_in[9];
    const float* g2    = (const float*)d_in[10];
    const float* bt2   = (const float*)d_in[11];

    float* stats1 = (float*)d_ws;                              // [64][256]
    float* stats2 = stats1 + NSLOT * 256;                      // [64][256]
    unsigned short* W1b = (unsigned short*)(stats2 + NSLOT * 256);  // 32768 bf16
    unsigned short* W2b = W1b + 32768;                         // 16384 bf16
    unsigned short* h   = W2b + 16384;                         // [B][E][D] bf16 (h, then h2 in-place)
    unsigned short* Pg  = (unsigned short*)d_out;              // [B][256][128] bf16 swizzled (64MB <= out 67MB)
    float* out    = (float*)d_out;

    hipMemsetAsync((void*)stats1, 0, 2 * NSLOT * 256 * sizeof(float), stream);
    k0_cvtw<<<dim3(128), dim3(256), 0, stream>>>(W1, W2, W1b, W2b);
    k1a_gemm<<<dim3(BB), dim3(1024), 0, stream>>>(gout, ss, es, Pg);
    k1b_stage2<<<dim3(BB), dim3(256), 0, stream>>>(Pg, W1b, b1, h, stats1);
    k3_gemm<<<dim3(BB), dim3(256), 0, stream>>>(h, W2b, b2, g1, bt1, stats1, stats2);
    k5_final<<<dim3(2048), dim3(256), 0, stream>>>(h, eout, g2, bt2, out, stats2);
}